// Round 6
// baseline (1626.977 us; speedup 1.0000x reference)
//
#include <hip/hip_runtime.h>
#include <hip/hip_bf16.h>

#define NN 20000
#define TT 60
#define DD 20
#define HH 128
#define KK 148      // DD + HH
#define EE 320000
#define EA 340000   // EE + NN (self loops)
#define ZSTRIDE 168 // z row stride in u16 (mult of 8 -> b128-aligned rows)

typedef unsigned short u16;
typedef unsigned int u32;
typedef __attribute__((ext_vector_type(8))) short bf16x8;  // 8 bf16 = 4 VGPRs
typedef __attribute__((ext_vector_type(4))) float f32x4;

__device__ __forceinline__ float bf2f(u16 u){ return __uint_as_float(((u32)u)<<16); }
__device__ __forceinline__ u16 f2bf(float f){   // RNE, values bounded (no NaN inputs)
  u32 x = __float_as_uint(f);
  return (u16)((x + 0x7FFFu + ((x >> 16) & 1u)) >> 16);
}
__device__ __forceinline__ float sigf(float x){
  return __builtin_amdgcn_rcpf(1.f + __expf(-x));
}
__device__ __forceinline__ float tanhf_fast(float x){
  return 1.f - 2.f*__builtin_amdgcn_rcpf(1.f + __expf(2.f*x));
}

// ---------------- prep: LSTM Wfrag (fused [Wih|Whh], MFMA B-layout) + bias --------------
__global__ void prep_lstm_kernel(const float* __restrict__ Wih, const float* __restrict__ Whh,
                                 const float* __restrict__ bih, const float* __restrict__ bhh,
                                 u16* __restrict__ Wfrag, float* __restrict__ bias){
  int idx = blockIdx.x*256 + threadIdx.x;
  if (idx < 8*4*5*64*8){
    int j    = idx & 7;
    int lane = (idx >> 3) & 63;
    int rest = idx >> 9;           // w*20 + q*5 + kt
    int kt = rest % 5, q = (rest/5) & 3, w = rest/20;
    int col = q*128 + w*16 + (lane & 15);
    int k   = kt*32 + ((lane >> 4) & 3)*8 + j;
    float v = 0.f;
    if (k < DD)       v = Wih[(size_t)col*DD + k];
    else if (k < KK)  v = Whh[(size_t)col*HH + (k - DD)];
    Wfrag[idx] = f2bf(v);
  }
  if (idx < 512) bias[idx] = bih[idx] + bhh[idx];
}

// ---------------- prep: GAT weight W[128][128] fp32 -> MFMA B-frag bf16 -----------------
__global__ void prep_w_kernel(const float* __restrict__ W, u16* __restrict__ Wf){
  int idx = blockIdx.x*256 + threadIdx.x;
  if (idx >= 8*4*64*8) return;
  int j = idx & 7, lane = (idx>>3) & 63, kt = (idx>>9) & 3, ct = idx>>11;
  int col = ct*16 + (lane & 15);
  int k   = kt*32 + ((lane>>4) & 3)*8 + j;
  Wf[idx] = f2bf(W[(size_t)k*128 + col]);
}

// ---------------- LSTM: MFMA recurrence, 32 nodes/block, 8 waves x 16 channels ----------
// launch_bounds(512,4): cap unified regs at 128 -> 2 blocks/CU co-resident.
__global__ __launch_bounds__(512, 4) void lstm_kernel(const float* __restrict__ xwin,
    const u16* __restrict__ Wfrag, const float* __restrict__ bias,
    u16* __restrict__ node_h){
  __shared__ u16 z[2][32][ZSTRIDE];   // [buf][node][ x(0..19) | h(20..147) | pad0 ]
  const int tid  = threadIdx.x;
  const int lane = tid & 63;
  const int w    = tid >> 6;
  const int nb   = blockIdx.x * 32;
  const int l15  = lane & 15;
  const int quad = lane >> 4;

  // ---- B fragments: 20 x bf16x8 = 80 regs, persistent across 60 steps ----
  bf16x8 B[4][5];
  {
    const bf16x8* bp = (const bf16x8*)Wfrag;
    #pragma unroll
    for (int q = 0; q < 4; q++)
      #pragma unroll
      for (int kt = 0; kt < 5; kt++)
        B[q][kt] = bp[(size_t)((w*20 + q*5 + kt)*64 + lane)];
  }
  float bg[4];
  #pragma unroll
  for (int q = 0; q < 4; q++) bg[q] = bias[q*128 + w*16 + l15];

  // ---- zero both z buffers ----
  for (int i = tid; i < 2*32*(ZSTRIDE/2); i += 512) ((u32*)(&z[0][0][0]))[i] = 0;

  // x loaders: 640 elems; thread covers {tid, tid+512}
  const int n0 = tid/20,  e0 = tid - n0*20;
  const int i1 = tid + 512;
  const int n1 = i1/20,   e1 = i1 - n1*20;
  const int has1 = (i1 < 640);
  const float* p0 = xwin + (size_t)(nb+n0)*(TT*DD) + e0;
  const float* p1 = xwin + (size_t)(nb + (has1 ? n1 : 0))*(TT*DD) + e1;

  __syncthreads();
  z[0][n0][e0] = f2bf(p0[0]);
  if (has1) z[0][n1][e1] = f2bf(p1[0]);

  f32x4 cst[2];
  const f32x4 zf = {0.f, 0.f, 0.f, 0.f};
  cst[0] = zf; cst[1] = zf;
  __syncthreads();

  #pragma unroll 1
  for (int t = 0; t < TT; t++){
    const int cur = t & 1, nxt = cur ^ 1;

    float xf0 = 0.f, xf1 = 0.f;
    if (t + 1 < TT){
      xf0 = p0[(t+1)*DD];
      if (has1) xf1 = p1[(t+1)*DD];
    }

    bf16x8 A[2][5];
    #pragma unroll
    for (int mt = 0; mt < 2; mt++)
      #pragma unroll
      for (int kt = 0; kt < 5; kt++)
        A[mt][kt] = *(const bf16x8*)&z[cur][mt*16 + l15][kt*32 + quad*8];

    f32x4 acc[2][4];
    #pragma unroll
    for (int mt = 0; mt < 2; mt++)
      #pragma unroll
      for (int q = 0; q < 4; q++){
        f32x4 a = __builtin_amdgcn_mfma_f32_16x16x32_bf16(A[mt][0], B[q][0], zf, 0,0,0);
        a = __builtin_amdgcn_mfma_f32_16x16x32_bf16(A[mt][1], B[q][1], a, 0,0,0);
        a = __builtin_amdgcn_mfma_f32_16x16x32_bf16(A[mt][2], B[q][2], a, 0,0,0);
        a = __builtin_amdgcn_mfma_f32_16x16x32_bf16(A[mt][3], B[q][3], a, 0,0,0);
        a = __builtin_amdgcn_mfma_f32_16x16x32_bf16(A[mt][4], B[q][4], a, 0,0,0);
        acc[mt][q] = a;
      }

    #pragma unroll
    for (int mt = 0; mt < 2; mt++){
      f32x4 cv = cst[mt];
      #pragma unroll
      for (int r = 0; r < 4; r++){
        float gi = acc[mt][0][r] + bg[0];
        float gf = acc[mt][1][r] + bg[1];
        float gg = acc[mt][2][r] + bg[2];
        float go = acc[mt][3][r] + bg[3];
        float cc = sigf(gf)*cv[r] + sigf(gi)*tanhf_fast(gg);
        cv[r] = cc;
        float h = sigf(go)*tanhf_fast(cc);
        const int row = mt*16 + quad*4 + r;
        u16 hb = f2bf(h);
        z[nxt][row][DD + w*16 + l15] = hb;
        if (t == TT-1)
          node_h[(size_t)(nb + row)*HH + w*16 + l15] = hb;
      }
      cst[mt] = cv;
    }

    if (t + 1 < TT){
      z[nxt][n0][e0] = f2bf(xf0);
      if (has1) z[nxt][n1][e1] = f2bf(xf1);
    }
    __syncthreads();
  }
}

// ---------------- MFMA GEMM: Y[M,128] bf16 = X[M,128] bf16 @ Wf (B-frags) ---------------
__global__ __launch_bounds__(256) void gemm_kernel(const u16* __restrict__ X,
    const u16* __restrict__ Wf, u16* __restrict__ Y){
  __shared__ u16 xs[32][136];           // +8 pad
  const int tid = threadIdx.x, lane = tid & 63, w = tid >> 6;
  const int l15 = lane & 15, quad = lane >> 4;
  const int rb  = blockIdx.x*32;

  for (int c = tid; c < 512; c += 256){
    int row = c >> 4, cc = c & 15;
    *(bf16x8*)&xs[row][cc*8] = *(const bf16x8*)&X[(size_t)(rb+row)*128 + cc*8];
  }
  bf16x8 Bf[2][4];
  #pragma unroll
  for (int ct = 0; ct < 2; ct++)
    #pragma unroll
    for (int kt = 0; kt < 4; kt++)
      Bf[ct][kt] = *(const bf16x8*)&Wf[(size_t)((((2*w+ct)*4 + kt)*64 + lane))*8];
  __syncthreads();

  bf16x8 A[2][4];
  #pragma unroll
  for (int mt = 0; mt < 2; mt++)
    #pragma unroll
    for (int kt = 0; kt < 4; kt++)
      A[mt][kt] = *(const bf16x8*)&xs[mt*16 + l15][kt*32 + quad*8];

  const f32x4 zf = {0.f,0.f,0.f,0.f};
  #pragma unroll
  for (int mt = 0; mt < 2; mt++)
    #pragma unroll
    for (int ct = 0; ct < 2; ct++){
      f32x4 a = __builtin_amdgcn_mfma_f32_16x16x32_bf16(A[mt][0], Bf[ct][0], zf, 0,0,0);
      a = __builtin_amdgcn_mfma_f32_16x16x32_bf16(A[mt][1], Bf[ct][1], a, 0,0,0);
      a = __builtin_amdgcn_mfma_f32_16x16x32_bf16(A[mt][2], Bf[ct][2], a, 0,0,0);
      a = __builtin_amdgcn_mfma_f32_16x16x32_bf16(A[mt][3], Bf[ct][3], a, 0,0,0);
      #pragma unroll
      for (int r = 0; r < 4; r++)
        Y[(size_t)(rb + mt*16 + quad*4 + r)*128 + (2*w+ct)*16 + l15] = f2bf(a[r]);
    }
}

// ---------------- per-node attention logits asr/adt [N,4] (XH bf16) --------------------
__global__ __launch_bounds__(256) void att_kernel(const u16* __restrict__ XH,
    const float* __restrict__ att_s, const float* __restrict__ att_d,
    float* __restrict__ asr, float* __restrict__ adt){
  __shared__ float as_[128], ad_[128];
  int tid = threadIdx.x;
  if (tid < 128){ as_[tid] = att_s[tid]; ad_[tid] = att_d[tid]; }
  __syncthreads();
  int n = blockIdx.x*64 + (tid>>2);
  int h = tid & 3;
  if (n >= NN) return;
  const u16* row = XH + (size_t)n*128 + h*32;
  float s = 0.f, d = 0.f;
  #pragma unroll
  for (int c = 0; c < 32; c++){
    float v = bf2f(row[c]);
    s = fmaf(v, as_[h*32+c], s);
    d = fmaf(v, ad_[h*32+c], d);
  }
  asr[n*4+h] = s; adt[n*4+h] = d;
}

// ---------------- CSR build -------------------------------------------------------------
__device__ __forceinline__ void edge_sd(int e, const int* src, const int* dst, int& s, int& d){
  if (e < EE){ s = src[e]; d = dst[e]; } else { s = e - EE; d = s; }
}

__global__ void deg_kernel(const int* __restrict__ src, const int* __restrict__ dst,
                           int* __restrict__ deg){
  int e = blockIdx.x*256 + threadIdx.x;
  if (e >= EA) return;
  int s, d; edge_sd(e, src, dst, s, d);
  atomicAdd(deg + d, 1);
}

__global__ __launch_bounds__(1024) void scan_kernel(const int* __restrict__ deg,
    int* __restrict__ rowptr, int* __restrict__ cursor){
  __shared__ int buf[1024];
  __shared__ int carry_s;
  const int tid = threadIdx.x;
  if (tid == 0) carry_s = 0;
  __syncthreads();
  for (int base = 0; base < NN; base += 1024){
    int idx = base + tid;
    int v = (idx < NN) ? deg[idx] : 0;
    buf[tid] = v;
    __syncthreads();
    #pragma unroll
    for (int off = 1; off < 1024; off <<= 1){
      int t = (tid >= off) ? buf[tid - off] : 0;
      __syncthreads();
      buf[tid] += t;
      __syncthreads();
    }
    int excl = buf[tid] - v;
    int c = carry_s;
    if (idx < NN){ rowptr[idx] = c + excl; cursor[idx] = c + excl; }
    int total = buf[1023];
    __syncthreads();
    if (tid == 0) carry_s = c + total;
    __syncthreads();
  }
  if (tid == 0) rowptr[NN] = carry_s;   // == EA
}

__global__ void fill_kernel(const int* __restrict__ src, const int* __restrict__ dst,
                            int* __restrict__ cursor, int* __restrict__ elist){
  int e = blockIdx.x*256 + threadIdx.x;
  if (e >= EA) return;
  int s, d; edge_sd(e, src, dst, s, d);
  int pos = atomicAdd(cursor + d, 1);
  elist[pos] = s;
}

// ---------------- fused GAT: 1-pass softmax+aggregate+bias+ELU (+optional head) ---------
// Logits bounded (|e| < ~2) -> no max-subtraction needed; denom >= exp(self) > 0.
__global__ __launch_bounds__(512) void gat_kernel(const int* __restrict__ rowptr,
    const int* __restrict__ elist, const float* __restrict__ asr,
    const float* __restrict__ adt, const u16* __restrict__ XH,
    const float* __restrict__ bias, u16* __restrict__ out,
    const float* __restrict__ Wh, const float* __restrict__ bh,
    float* __restrict__ outf){
  const int tid = threadIdx.x, lane = tid & 63, w = tid >> 6;
  const int d = blockIdx.x*8 + w;            // NN % 8 == 0
  const int r0 = rowptr[d], r1 = rowptr[d+1];
  const int h = lane >> 4;
  const int c = lane*2;
  float4 ad4 = *(const float4*)(adt + (size_t)d*4);
  const float adh = (h==0) ? ad4.x : (h==1) ? ad4.y : (h==2) ? ad4.z : ad4.w;

  float den = 0.f, accx = 0.f, accy = 0.f;
  for (int idx = r0; idx < r1; idx++){
    int s = elist[idx];
    float4 a = *(const float4*)(asr + (size_t)s*4);
    float av = (h==0) ? a.x : (h==1) ? a.y : (h==2) ? a.z : a.w;
    float l = av + adh; l = l > 0.f ? l : 0.2f*l;
    float ex = __expf(l);
    den += ex;
    u32 pk = ((const u32*)XH)[(size_t)s*64 + lane];
    accx = fmaf(ex, bf2f((u16)pk),        accx);
    accy = fmaf(ex, bf2f((u16)(pk>>16)),  accy);
  }
  float rd = __builtin_amdgcn_rcpf(den);
  float vx = accx*rd + bias[c], vy = accy*rd + bias[c+1];
  vx = vx > 0.f ? vx : __expf(vx) - 1.f;
  vy = vy > 0.f ? vy : __expf(vy) - 1.f;

  if (Wh == nullptr){
    u32 pk = (u32)f2bf(vx) | ((u32)f2bf(vy) << 16);
    ((u32*)out)[(size_t)d*64 + lane] = pk;
  } else {
    // fused head: out[d] = ELU(h) @ Wh + bh  (wave shuffle-reduce over 128 channels)
    float p0 = vx*Wh[c*2]   + vy*Wh[c*2+2];
    float p1 = vx*Wh[c*2+1] + vy*Wh[c*2+3];
    #pragma unroll
    for (int off = 32; off > 0; off >>= 1){
      p0 += __shfl_xor(p0, off);
      p1 += __shfl_xor(p1, off);
    }
    if (lane == 0){
      float2 o; o.x = p0 + bh[0]; o.y = p1 + bh[1];
      ((float2*)outf)[d] = o;
    }
  }
}

// ---------------- launch ----------------------------------------------------------------
extern "C" void kernel_launch(void* const* d_in, const int* in_sizes, int n_in,
                              void* d_out, int out_size, void* d_ws, size_t ws_size,
                              hipStream_t stream){
  const float* xwin = (const float*)d_in[0];
  const int*   eidx = (const int*)d_in[1];
  const float* Wih  = (const float*)d_in[2];
  const float* Whh  = (const float*)d_in[3];
  const float* bih  = (const float*)d_in[4];
  const float* bhh  = (const float*)d_in[5];
  const float* W1   = (const float*)d_in[6];
  const float* as1  = (const float*)d_in[7];
  const float* ad1  = (const float*)d_in[8];
  const float* b1   = (const float*)d_in[9];
  const float* W2   = (const float*)d_in[10];
  const float* as2  = (const float*)d_in[11];
  const float* ad2  = (const float*)d_in[12];
  const float* b2   = (const float*)d_in[13];
  const float* Wh   = (const float*)d_in[14];
  const float* bh   = (const float*)d_in[15];
  const int* src = eidx;
  const int* dst = eidx + EE;

  char* ws = (char*)d_ws;
  size_t off = 0;
  auto alloc = [&](size_t bytes)->void*{
    void* p = ws + off; off += (bytes + 255) & ~(size_t)255; return p;
  };
  u16*   WfL   = (u16*)  alloc((size_t)8*4*5*64*8*sizeof(u16));
  u16*   W1f   = (u16*)  alloc((size_t)8*4*64*8*sizeof(u16));
  u16*   W2f   = (u16*)  alloc((size_t)8*4*64*8*sizeof(u16));
  float* bias  = (float*)alloc(512*sizeof(float));
  u16*   nodeh = (u16*)  alloc((size_t)NN*128*sizeof(u16));
  u16*   xh    = (u16*)  alloc((size_t)NN*128*sizeof(u16));
  u16*   hbuf  = (u16*)  alloc((size_t)NN*128*sizeof(u16));
  float* asr   = (float*)alloc((size_t)NN*4*sizeof(float));
  float* adt   = (float*)alloc((size_t)NN*4*sizeof(float));
  int*   deg   = (int*)  alloc((size_t)NN*sizeof(int));
  int*   rowp  = (int*)  alloc((size_t)(NN+1)*sizeof(int));
  int*   curs  = (int*)  alloc((size_t)NN*sizeof(int));
  int*   elist = (int*)  alloc((size_t)EA*sizeof(int));
  (void)ws_size; (void)in_sizes; (void)n_in; (void)out_size;

  const int EGRID = (EA+255)/256;

  // weight prep + CSR build
  prep_lstm_kernel<<<(8*4*5*64*8+255)/256, 256, 0, stream>>>(Wih, Whh, bih, bhh, WfL, bias);
  prep_w_kernel<<<(8*4*64*8+255)/256, 256, 0, stream>>>(W1, W1f);
  prep_w_kernel<<<(8*4*64*8+255)/256, 256, 0, stream>>>(W2, W2f);
  hipMemsetAsync(deg, 0, (size_t)NN*sizeof(int), stream);
  deg_kernel<<<EGRID, 256, 0, stream>>>(src, dst, deg);
  scan_kernel<<<1, 1024, 0, stream>>>(deg, rowp, curs);
  fill_kernel<<<EGRID, 256, 0, stream>>>(src, dst, curs, elist);

  // LSTM
  lstm_kernel<<<NN/32, 512, 0, stream>>>(xwin, WfL, bias, nodeh);

  // GAT layer 1
  gemm_kernel<<<NN/32, 256, 0, stream>>>(nodeh, W1f, xh);
  att_kernel<<<(NN+63)/64, 256, 0, stream>>>(xh, as1, ad1, asr, adt);
  gat_kernel<<<NN/8, 512, 0, stream>>>(rowp, elist, asr, adt, xh, b1, hbuf,
                                       nullptr, nullptr, nullptr);
  // GAT layer 2 (+fused head)
  gemm_kernel<<<NN/32, 256, 0, stream>>>(hbuf, W2f, xh);
  att_kernel<<<(NN+63)/64, 256, 0, stream>>>(xh, as2, ad2, asr, adt);
  gat_kernel<<<NN/8, 512, 0, stream>>>(rowp, elist, asr, adt, xh, b2, nullptr,
                                       Wh, bh, (float*)d_out);
}

// Round 7
// 961.120 us; speedup vs baseline: 1.6928x; 1.6928x over previous
//
#include <hip/hip_runtime.h>
#include <hip/hip_bf16.h>

#define NN 20000
#define TT 60
#define DD 20
#define HH 128
#define KK 148      // DD + HH
#define EE 320000
#define EA 340000   // EE + NN (self loops)
#define ZSTRIDE 168 // z row stride in u16 (mult of 8 -> b128-aligned rows)

typedef unsigned short u16;
typedef unsigned int u32;
typedef __attribute__((ext_vector_type(8))) short bf16x8;  // 8 bf16 = 4 VGPRs
typedef __attribute__((ext_vector_type(4))) float f32x4;

__device__ __forceinline__ float bf2f(u16 u){ return __uint_as_float(((u32)u)<<16); }
__device__ __forceinline__ u16 f2bf(float f){   // RNE, values bounded (no NaN inputs)
  u32 x = __float_as_uint(f);
  return (u16)((x + 0x7FFFu + ((x >> 16) & 1u)) >> 16);
}
__device__ __forceinline__ float sigf(float x){
  return __builtin_amdgcn_rcpf(1.f + __expf(-x));
}
__device__ __forceinline__ float tanhf_fast(float x){
  return 1.f - 2.f*__builtin_amdgcn_rcpf(1.f + __expf(2.f*x));
}

// ---------------- prep: LSTM Wfrag for 16-wave gate-split layout + bias -----------------
// wave w in [0,16): slice s=w&7 (ch 16s..16s+15), gate-pair gp=w>>3 (0:{i,f} 1:{g,o})
// Wfrag[((w*10 + gi*5 + kt)*64 + lane)*8 + j]:
//   gate=2*gp+gi; col=gate*128 + s*16 + (lane&15); k=kt*32 + ((lane>>4)&3)*8 + j
__global__ void prep_lstm_kernel(const float* __restrict__ Wih, const float* __restrict__ Whh,
                                 const float* __restrict__ bih, const float* __restrict__ bhh,
                                 u16* __restrict__ Wfrag, float* __restrict__ bias){
  int idx = blockIdx.x*256 + threadIdx.x;
  if (idx < 16*10*64*8){
    int j    = idx & 7;
    int lane = (idx >> 3) & 63;
    int rest = idx >> 9;           // w*10 + gi*5 + kt
    int kt = rest % 5, gi = (rest/5) & 1, w = rest/10;
    int s = w & 7, gp = w >> 3;
    int gate = 2*gp + gi;
    int col = gate*128 + s*16 + (lane & 15);
    int k   = kt*32 + ((lane >> 4) & 3)*8 + j;
    float v = 0.f;
    if (k < DD)       v = Wih[(size_t)col*DD + k];
    else if (k < KK)  v = Whh[(size_t)col*HH + (k - DD)];
    Wfrag[idx] = f2bf(v);
  }
  if (idx < 512) bias[idx] = bih[idx] + bhh[idx];
}

// ---------------- prep: GAT weights W[128][128] -> MFMA B-frag bf16 (both layers) -------
__global__ void prep_w_kernel(const float* __restrict__ W1, const float* __restrict__ W2,
                              u16* __restrict__ W1f, u16* __restrict__ W2f){
  int idx = blockIdx.x*256 + threadIdx.x;
  const float* W = W1; u16* Wf = W1f;
  if (idx >= 8*4*64*8){ idx -= 8*4*64*8; W = W2; Wf = W2f; }
  int j = idx & 7, lane = (idx>>3) & 63, kt = (idx>>9) & 3, ct = idx>>11;
  int col = ct*16 + (lane & 15);
  int k   = kt*32 + ((lane>>4) & 3)*8 + j;
  Wf[idx] = f2bf(W[(size_t)k*128 + col]);
}

// ---------------- LSTM: 32 nodes/block, 1024 threads (16 waves), gate-split -------------
// Wave (s,gp): B = 2 gates x 5 kt = 40 regs. Computes its 2 gates for BOTH 16-node
// tiles; keeps tile mt=gp, ships tile mt=1-gp to partner via LDS; epilogues 4 out/lane.
__global__ __launch_bounds__(1024) void lstm_kernel(const float* __restrict__ xwin,
    const u16* __restrict__ Wfrag, const float* __restrict__ bias,
    u16* __restrict__ node_h){
  __shared__ u16 z[2][32][ZSTRIDE];          // 21504 B
  __shared__ float xchg[8][2][2][64][4];     // 16384 B: [s][gp_writer][gi][lane][r]
  const int tid  = threadIdx.x;
  const int lane = tid & 63;
  const int w    = tid >> 6;
  const int s    = w & 7;
  const int gp   = w >> 3;
  const int nb   = blockIdx.x * 32;
  const int l15  = lane & 15;
  const int quad = lane >> 4;

  // ---- B fragments: 10 x bf16x8 = 40 regs, persistent across 60 steps ----
  bf16x8 B[2][5];
  {
    const bf16x8* bp = (const bf16x8*)Wfrag;
    #pragma unroll
    for (int gi = 0; gi < 2; gi++)
      #pragma unroll
      for (int kt = 0; kt < 5; kt++)
        B[gi][kt] = bp[(size_t)((w*10 + gi*5 + kt)*64 + lane)];
  }
  float bg[4];
  #pragma unroll
  for (int q = 0; q < 4; q++) bg[q] = bias[q*128 + s*16 + l15];

  // ---- zero both z buffers ----
  for (int i = tid; i < 2*32*(ZSTRIDE/2); i += 1024) ((u32*)(&z[0][0][0]))[i] = 0;

  // x loader: 640 elems, threads tid<640 own one (node,elem)
  const int xact = (tid < 640);
  const int n0 = tid/20, e0 = tid - n0*20;
  const float* p0 = xwin + (size_t)(nb + (xact ? n0 : 0))*(TT*DD) + e0;

  __syncthreads();
  if (xact) z[0][n0][e0] = f2bf(p0[0]);

  f32x4 cst = {0.f, 0.f, 0.f, 0.f};
  const f32x4 zf = {0.f, 0.f, 0.f, 0.f};
  __syncthreads();

  #pragma unroll 1
  for (int t = 0; t < TT; t++){
    const int cur = t & 1, nxt = cur ^ 1;

    float xf0 = 0.f;
    if (xact && t + 1 < TT) xf0 = p0[(t+1)*DD];

    // ---- MFMA: own 2 gates for both node tiles ----
    f32x4 acc[2][2];
    #pragma unroll
    for (int mt = 0; mt < 2; mt++){
      bf16x8 A[5];
      #pragma unroll
      for (int kt = 0; kt < 5; kt++)
        A[kt] = *(const bf16x8*)&z[cur][mt*16 + l15][kt*32 + quad*8];
      #pragma unroll
      for (int gi = 0; gi < 2; gi++){
        f32x4 a = __builtin_amdgcn_mfma_f32_16x16x32_bf16(A[0], B[gi][0], zf, 0,0,0);
        a = __builtin_amdgcn_mfma_f32_16x16x32_bf16(A[1], B[gi][1], a, 0,0,0);
        a = __builtin_amdgcn_mfma_f32_16x16x32_bf16(A[2], B[gi][2], a, 0,0,0);
        a = __builtin_amdgcn_mfma_f32_16x16x32_bf16(A[3], B[gi][3], a, 0,0,0);
        a = __builtin_amdgcn_mfma_f32_16x16x32_bf16(A[4], B[gi][4], a, 0,0,0);
        acc[mt][gi] = a;
      }
    }

    // ---- ship other-mt tiles to partner ----
    const int mto = 1 - gp;
    *(f32x4*)&xchg[s][gp][0][lane][0] = acc[mto][0];
    *(f32x4*)&xchg[s][gp][1][lane][0] = acc[mto][1];
    __syncthreads();
    f32x4 pg0 = *(const f32x4*)&xchg[s][1-gp][0][lane][0];
    f32x4 pg1 = *(const f32x4*)&xchg[s][1-gp][1][lane][0];

    // gate quad for epilogue tile mt=gp (wave-uniform select)
    f32x4 gI, gF, gG, gO;
    if (gp == 0){ gI = acc[0][0]; gF = acc[0][1]; gG = pg0; gO = pg1; }
    else        { gG = acc[1][0]; gO = acc[1][1]; gI = pg0; gF = pg1; }

    #pragma unroll
    for (int r = 0; r < 4; r++){
      float gi = gI[r] + bg[0];
      float gf = gF[r] + bg[1];
      float gg = gG[r] + bg[2];
      float go = gO[r] + bg[3];
      float cc = sigf(gf)*cst[r] + sigf(gi)*tanhf_fast(gg);
      cst[r] = cc;
      float h = sigf(go)*tanhf_fast(cc);
      const int row = gp*16 + quad*4 + r;
      u16 hb = f2bf(h);
      z[nxt][row][DD + s*16 + l15] = hb;
      if (t == TT-1)
        node_h[(size_t)(nb + row)*HH + s*16 + l15] = hb;
    }

    if (xact && t + 1 < TT) z[nxt][n0][e0] = f2bf(xf0);
    __syncthreads();
  }
}

// ---------------- MFMA GEMM: Y[M,128] bf16 = X[M,128] bf16 @ Wf (B-frags) ---------------
__global__ __launch_bounds__(256) void gemm_kernel(const u16* __restrict__ X,
    const u16* __restrict__ Wf, u16* __restrict__ Y){
  __shared__ u16 xs[32][136];           // +8 pad
  const int tid = threadIdx.x, lane = tid & 63, w = tid >> 6;
  const int l15 = lane & 15, quad = lane >> 4;
  const int rb  = blockIdx.x*32;

  for (int c = tid; c < 512; c += 256){
    int row = c >> 4, cc = c & 15;
    *(bf16x8*)&xs[row][cc*8] = *(const bf16x8*)&X[(size_t)(rb+row)*128 + cc*8];
  }
  bf16x8 Bf[2][4];
  #pragma unroll
  for (int ct = 0; ct < 2; ct++)
    #pragma unroll
    for (int kt = 0; kt < 4; kt++)
      Bf[ct][kt] = *(const bf16x8*)&Wf[(size_t)((((2*w+ct)*4 + kt)*64 + lane))*8];
  __syncthreads();

  bf16x8 A[2][4];
  #pragma unroll
  for (int mt = 0; mt < 2; mt++)
    #pragma unroll
    for (int kt = 0; kt < 4; kt++)
      A[mt][kt] = *(const bf16x8*)&xs[mt*16 + l15][kt*32 + quad*8];

  const f32x4 zf = {0.f,0.f,0.f,0.f};
  #pragma unroll
  for (int mt = 0; mt < 2; mt++)
    #pragma unroll
    for (int ct = 0; ct < 2; ct++){
      f32x4 a = __builtin_amdgcn_mfma_f32_16x16x32_bf16(A[mt][0], Bf[ct][0], zf, 0,0,0);
      a = __builtin_amdgcn_mfma_f32_16x16x32_bf16(A[mt][1], Bf[ct][1], a, 0,0,0);
      a = __builtin_amdgcn_mfma_f32_16x16x32_bf16(A[mt][2], Bf[ct][2], a, 0,0,0);
      a = __builtin_amdgcn_mfma_f32_16x16x32_bf16(A[mt][3], Bf[ct][3], a, 0,0,0);
      #pragma unroll
      for (int r = 0; r < 4; r++)
        Y[(size_t)(rb + mt*16 + quad*4 + r)*128 + (2*w+ct)*16 + l15] = f2bf(a[r]);
    }
}

// ---------------- per-node attention logits asr/adt [N,4] (XH bf16, b128 loads) ---------
__global__ __launch_bounds__(256) void att_kernel(const u16* __restrict__ XH,
    const float* __restrict__ att_s, const float* __restrict__ att_d,
    float* __restrict__ asr, float* __restrict__ adt){
  __shared__ float as_[128], ad_[128];
  int tid = threadIdx.x;
  if (tid < 128){ as_[tid] = att_s[tid]; ad_[tid] = att_d[tid]; }
  __syncthreads();
  int n = blockIdx.x*64 + (tid>>2);
  int h = tid & 3;
  if (n >= NN) return;
  const u16* row = XH + (size_t)n*128 + h*32;
  float sv = 0.f, dv = 0.f;
  #pragma unroll
  for (int blk = 0; blk < 4; blk++){
    bf16x8 v = *(const bf16x8*)(row + blk*8);
    #pragma unroll
    for (int j = 0; j < 8; j++){
      float x = bf2f((u16)v[j]);
      sv = fmaf(x, as_[h*32 + blk*8 + j], sv);
      dv = fmaf(x, ad_[h*32 + blk*8 + j], dv);
    }
  }
  asr[n*4+h] = sv; adt[n*4+h] = dv;
}

// ---------------- CSR build (parallel scan) ---------------------------------------------
__device__ __forceinline__ void edge_sd(int e, const int* src, const int* dst, int& s, int& d){
  if (e < EE){ s = src[e]; d = dst[e]; } else { s = e - EE; d = s; }
}

__global__ void deg_kernel(const int* __restrict__ src, const int* __restrict__ dst,
                           int* __restrict__ deg){
  int e = blockIdx.x*256 + threadIdx.x;
  if (e >= EA) return;
  int s, d; edge_sd(e, src, dst, s, d);
  atomicAdd(deg + d, 1);
}

#define SCB 80   // ceil(NN/256)
__global__ __launch_bounds__(256) void psum_kernel(const int* __restrict__ deg,
                                                   int* __restrict__ psum){
  __shared__ int ws[4];
  int i = blockIdx.x*256 + threadIdx.x;
  int v = (i < NN) ? deg[i] : 0;
  #pragma unroll
  for (int off = 32; off > 0; off >>= 1) v += __shfl_down(v, off);
  if ((threadIdx.x & 63) == 0) ws[threadIdx.x >> 6] = v;
  __syncthreads();
  if (threadIdx.x == 0) psum[blockIdx.x] = ws[0]+ws[1]+ws[2]+ws[3];
}

__global__ void pscan_kernel(const int* __restrict__ psum, int* __restrict__ boff,
                             int* __restrict__ rowptr){
  if (threadIdx.x == 0){
    int acc = 0;
    for (int b = 0; b < SCB; b++){ boff[b] = acc; acc += psum[b]; }
    boff[SCB] = acc;
    rowptr[NN] = acc;   // == EA
  }
}

__global__ __launch_bounds__(256) void rowptr_kernel(const int* __restrict__ deg,
    const int* __restrict__ boff, int* __restrict__ rowptr, int* __restrict__ cursor){
  __shared__ int buf[256];
  const int tid = threadIdx.x;
  int i = blockIdx.x*256 + tid;
  int v = (i < NN) ? deg[i] : 0;
  buf[tid] = v;
  __syncthreads();
  #pragma unroll
  for (int off = 1; off < 256; off <<= 1){
    int t = (tid >= off) ? buf[tid - off] : 0;
    __syncthreads();
    buf[tid] += t;
    __syncthreads();
  }
  if (i < NN){
    int excl = buf[tid] - v + boff[blockIdx.x];
    rowptr[i] = excl; cursor[i] = excl;
  }
}

__global__ void fill_kernel(const int* __restrict__ src, const int* __restrict__ dst,
                            int* __restrict__ cursor, int* __restrict__ elist){
  int e = blockIdx.x*256 + threadIdx.x;
  if (e >= EA) return;
  int s, d; edge_sd(e, src, dst, s, d);
  int pos = atomicAdd(cursor + d, 1);
  elist[pos] = s;
}

// ---------------- fused GAT: 1-pass softmax+aggregate+bias+ELU (+optional head) ---------
__global__ __launch_bounds__(512) void gat_kernel(const int* __restrict__ rowptr,
    const int* __restrict__ elist, const float* __restrict__ asr,
    const float* __restrict__ adt, const u16* __restrict__ XH,
    const float* __restrict__ bias, u16* __restrict__ out,
    const float* __restrict__ Wh, const float* __restrict__ bh,
    float* __restrict__ outf){
  const int tid = threadIdx.x, lane = tid & 63, w = tid >> 6;
  const int d = blockIdx.x*8 + w;            // NN % 8 == 0
  const int r0 = rowptr[d], r1 = rowptr[d+1];
  const int h = lane >> 4;
  const int c = lane*2;
  float4 ad4 = *(const float4*)(adt + (size_t)d*4);
  const float adh = (h==0) ? ad4.x : (h==1) ? ad4.y : (h==2) ? ad4.z : ad4.w;

  float den = 0.f, accx = 0.f, accy = 0.f;
  // software-pipelined edge loop (>=1 edge guaranteed: self loop)
  int s_cur = elist[r0];
  float4 a_cur = *(const float4*)(asr + (size_t)s_cur*4);
  u32 pk_cur = ((const u32*)XH)[(size_t)s_cur*64 + lane];
  for (int idx = r0; idx < r1; idx++){
    int s_nxt = (idx+1 < r1) ? elist[idx+1] : s_cur;
    float4 a_nxt = *(const float4*)(asr + (size_t)s_nxt*4);
    u32 pk_nxt = ((const u32*)XH)[(size_t)s_nxt*64 + lane];
    float av = (h==0) ? a_cur.x : (h==1) ? a_cur.y : (h==2) ? a_cur.z : a_cur.w;
    float l = av + adh; l = l > 0.f ? l : 0.2f*l;
    float ex = __expf(l);
    den += ex;
    accx = fmaf(ex, bf2f((u16)pk_cur),       accx);
    accy = fmaf(ex, bf2f((u16)(pk_cur>>16)), accy);
    a_cur = a_nxt; pk_cur = pk_nxt; s_cur = s_nxt;
  }
  float rd = __builtin_amdgcn_rcpf(den);
  float vx = accx*rd + bias[c], vy = accy*rd + bias[c+1];
  vx = vx > 0.f ? vx : __expf(vx) - 1.f;
  vy = vy > 0.f ? vy : __expf(vy) - 1.f;

  if (Wh == nullptr){
    u32 pk = (u32)f2bf(vx) | ((u32)f2bf(vy) << 16);
    ((u32*)out)[(size_t)d*64 + lane] = pk;
  } else {
    float p0 = vx*Wh[c*2]   + vy*Wh[c*2+2];
    float p1 = vx*Wh[c*2+1] + vy*Wh[c*2+3];
    #pragma unroll
    for (int off = 32; off > 0; off >>= 1){
      p0 += __shfl_xor(p0, off);
      p1 += __shfl_xor(p1, off);
    }
    if (lane == 0){
      float2 o; o.x = p0 + bh[0]; o.y = p1 + bh[1];
      ((float2*)outf)[d] = o;
    }
  }
}

// ---------------- launch ----------------------------------------------------------------
extern "C" void kernel_launch(void* const* d_in, const int* in_sizes, int n_in,
                              void* d_out, int out_size, void* d_ws, size_t ws_size,
                              hipStream_t stream){
  const float* xwin = (const float*)d_in[0];
  const int*   eidx = (const int*)d_in[1];
  const float* Wih  = (const float*)d_in[2];
  const float* Whh  = (const float*)d_in[3];
  const float* bih  = (const float*)d_in[4];
  const float* bhh  = (const float*)d_in[5];
  const float* W1   = (const float*)d_in[6];
  const float* as1  = (const float*)d_in[7];
  const float* ad1  = (const float*)d_in[8];
  const float* b1   = (const float*)d_in[9];
  const float* W2   = (const float*)d_in[10];
  const float* as2  = (const float*)d_in[11];
  const float* ad2  = (const float*)d_in[12];
  const float* b2   = (const float*)d_in[13];
  const float* Wh   = (const float*)d_in[14];
  const float* bh   = (const float*)d_in[15];
  const int* src = eidx;
  const int* dst = eidx + EE;

  char* ws = (char*)d_ws;
  size_t off = 0;
  auto alloc = [&](size_t bytes)->void*{
    void* p = ws + off; off += (bytes + 255) & ~(size_t)255; return p;
  };
  u16*   WfL   = (u16*)  alloc((size_t)16*10*64*8*sizeof(u16));
  u16*   W1f   = (u16*)  alloc((size_t)8*4*64*8*sizeof(u16));
  u16*   W2f   = (u16*)  alloc((size_t)8*4*64*8*sizeof(u16));
  float* bias  = (float*)alloc(512*sizeof(float));
  u16*   nodeh = (u16*)  alloc((size_t)NN*128*sizeof(u16));
  u16*   xh    = (u16*)  alloc((size_t)NN*128*sizeof(u16));
  u16*   hbuf  = (u16*)  alloc((size_t)NN*128*sizeof(u16));
  float* asr   = (float*)alloc((size_t)NN*4*sizeof(float));
  float* adt   = (float*)alloc((size_t)NN*4*sizeof(float));
  int*   deg   = (int*)  alloc((size_t)NN*sizeof(int));
  int*   rowp  = (int*)  alloc((size_t)(NN+1)*sizeof(int));
  int*   curs  = (int*)  alloc((size_t)NN*sizeof(int));
  int*   psum  = (int*)  alloc((size_t)SCB*sizeof(int));
  int*   boff  = (int*)  alloc((size_t)(SCB+1)*sizeof(int));
  int*   elist = (int*)  alloc((size_t)EA*sizeof(int));
  (void)ws_size; (void)in_sizes; (void)n_in; (void)out_size;

  const int EGRID = (EA+255)/256;

  // weight prep + CSR build
  prep_lstm_kernel<<<(16*10*64*8+255)/256, 256, 0, stream>>>(Wih, Whh, bih, bhh, WfL, bias);
  prep_w_kernel<<<(2*8*4*64*8+255)/256, 256, 0, stream>>>(W1, W2, W1f, W2f);
  hipMemsetAsync(deg, 0, (size_t)NN*sizeof(int), stream);
  deg_kernel<<<EGRID, 256, 0, stream>>>(src, dst, deg);
  psum_kernel<<<SCB, 256, 0, stream>>>(deg, psum);
  pscan_kernel<<<1, 64, 0, stream>>>(psum, boff, rowp);
  rowptr_kernel<<<SCB, 256, 0, stream>>>(deg, boff, rowp, curs);
  fill_kernel<<<EGRID, 256, 0, stream>>>(src, dst, curs, elist);

  // LSTM
  lstm_kernel<<<NN/32, 1024, 0, stream>>>(xwin, WfL, bias, nodeh);

  // GAT layer 1
  gemm_kernel<<<NN/32, 256, 0, stream>>>(nodeh, W1f, xh);
  att_kernel<<<(NN+63)/64, 256, 0, stream>>>(xh, as1, ad1, asr, adt);
  gat_kernel<<<NN/8, 512, 0, stream>>>(rowp, elist, asr, adt, xh, b1, hbuf,
                                       nullptr, nullptr, nullptr);
  // GAT layer 2 (+fused head)
  gemm_kernel<<<NN/32, 256, 0, stream>>>(hbuf, W2f, xh);
  att_kernel<<<(NN+63)/64, 256, 0, stream>>>(xh, as2, ad2, asr, adt);
  gat_kernel<<<NN/8, 512, 0, stream>>>(rowp, elist, asr, adt, xh, b2, nullptr,
                                       Wh, bh, (float*)d_out);
}

// Round 8
// 637.705 us; speedup vs baseline: 2.5513x; 1.5072x over previous
//
#include <hip/hip_runtime.h>
#include <hip/hip_bf16.h>

#define NN 20000
#define TT 60
#define DD 20
#define HH 128
#define KK 148      // DD + HH
#define EE 320000
#define EA 340000   // EE + NN (self loops)
#define ZSTRIDE 168 // z row stride in u16 (mult of 8 -> b128-aligned rows)

typedef unsigned short u16;
typedef unsigned int u32;
typedef __attribute__((ext_vector_type(8))) short bf16x8;  // 8 bf16 = 4 VGPRs
typedef __attribute__((ext_vector_type(4))) float f32x4;

__device__ __forceinline__ float bf2f(u16 u){ return __uint_as_float(((u32)u)<<16); }
__device__ __forceinline__ u16 f2bf(float f){   // RNE, values bounded (no NaN inputs)
  u32 x = __float_as_uint(f);
  return (u16)((x + 0x7FFFu + ((x >> 16) & 1u)) >> 16);
}
__device__ __forceinline__ float sigf(float x){
  return __builtin_amdgcn_rcpf(1.f + __expf(-x));
}
__device__ __forceinline__ float tanhf_fast(float x){
  return 1.f - 2.f*__builtin_amdgcn_rcpf(1.f + __expf(2.f*x));
}

// ---------------- prep: LSTM Wfrag (8-wave layout: wave w owns 16 ch x 4 gates) ---------
// Wfrag[((w*20 + q*5 + kt)*64 + lane)*8 + j]; col=q*128+w*16+(lane&15); k=kt*32+(lane>>4)*8+j
__global__ void prep_lstm_kernel(const float* __restrict__ Wih, const float* __restrict__ Whh,
                                 const float* __restrict__ bih, const float* __restrict__ bhh,
                                 u16* __restrict__ Wfrag, float* __restrict__ bias){
  int idx = blockIdx.x*256 + threadIdx.x;
  if (idx < 8*4*5*64*8){
    int j    = idx & 7;
    int lane = (idx >> 3) & 63;
    int rest = idx >> 9;           // w*20 + q*5 + kt
    int kt = rest % 5, q = (rest/5) & 3, w = rest/20;
    int col = q*128 + w*16 + (lane & 15);
    int k   = kt*32 + ((lane >> 4) & 3)*8 + j;
    float v = 0.f;
    if (k < DD)       v = Wih[(size_t)col*DD + k];
    else if (k < KK)  v = Whh[(size_t)col*HH + (k - DD)];
    Wfrag[idx] = f2bf(v);
  }
  if (idx < 512) bias[idx] = bih[idx] + bhh[idx];
}

// ---------------- prep: GAT weights W[128][128] -> MFMA B-frag bf16 (both layers) -------
__global__ void prep_w_kernel(const float* __restrict__ W1, const float* __restrict__ W2,
                              u16* __restrict__ W1f, u16* __restrict__ W2f){
  int idx = blockIdx.x*256 + threadIdx.x;
  const float* W = W1; u16* Wf = W1f;
  if (idx >= 8*4*64*8){ idx -= 8*4*64*8; W = W2; Wf = W2f; }
  int j = idx & 7, lane = (idx>>3) & 63, kt = (idx>>9) & 3, ct = idx>>11;
  int col = ct*16 + (lane & 15);
  int k   = kt*32 + ((lane>>4) & 3)*8 + j;
  Wf[idx] = f2bf(W[(size_t)k*128 + col]);
}

// ---------------- LSTM: MFMA recurrence, 32 nodes/block, 8 waves x 16 channels ----------
// R4 structure (measured 471 us): B-frags 80 regs/wave register-resident, double-buffered
// z, 1 barrier/step. (512,2): 256-reg cap, no spill; ~1 block/CU packed.
__global__ __launch_bounds__(512, 2) void lstm_kernel(const float* __restrict__ xwin,
    const u16* __restrict__ Wfrag, const float* __restrict__ bias,
    u16* __restrict__ node_h){
  __shared__ u16 z[2][32][ZSTRIDE];   // [buf][node][ x(0..19) | h(20..147) | pad0 ]
  const int tid  = threadIdx.x;
  const int lane = tid & 63;
  const int w    = tid >> 6;
  const int nb   = blockIdx.x * 32;
  const int l15  = lane & 15;
  const int quad = lane >> 4;

  // ---- B fragments: 20 x bf16x8 = 80 regs, persistent across 60 steps ----
  bf16x8 B[4][5];
  {
    const bf16x8* bp = (const bf16x8*)Wfrag;
    #pragma unroll
    for (int q = 0; q < 4; q++)
      #pragma unroll
      for (int kt = 0; kt < 5; kt++)
        B[q][kt] = bp[(size_t)((w*20 + q*5 + kt)*64 + lane)];
  }
  float bg[4];
  #pragma unroll
  for (int q = 0; q < 4; q++) bg[q] = bias[q*128 + w*16 + l15];

  // ---- zero both z buffers ----
  for (int i = tid; i < 2*32*(ZSTRIDE/2); i += 512) ((u32*)(&z[0][0][0]))[i] = 0;

  // x loaders: 640 elems; thread covers {tid, tid+512}
  const int n0 = tid/20,  e0 = tid - n0*20;
  const int i1 = tid + 512;
  const int n1 = i1/20,   e1 = i1 - n1*20;
  const int has1 = (i1 < 640);
  const float* p0 = xwin + (size_t)(nb+n0)*(TT*DD) + e0;
  const float* p1 = xwin + (size_t)(nb + (has1 ? n1 : 0))*(TT*DD) + e1;

  __syncthreads();
  z[0][n0][e0] = f2bf(p0[0]);
  if (has1) z[0][n1][e1] = f2bf(p1[0]);

  f32x4 cst[2];
  const f32x4 zf = {0.f, 0.f, 0.f, 0.f};
  cst[0] = zf; cst[1] = zf;
  __syncthreads();

  #pragma unroll 1
  for (int t = 0; t < TT; t++){
    const int cur = t & 1, nxt = cur ^ 1;

    float xf0 = 0.f, xf1 = 0.f;
    if (t + 1 < TT){
      xf0 = p0[(t+1)*DD];
      if (has1) xf1 = p1[(t+1)*DD];
    }

    bf16x8 A[2][5];
    #pragma unroll
    for (int mt = 0; mt < 2; mt++)
      #pragma unroll
      for (int kt = 0; kt < 5; kt++)
        A[mt][kt] = *(const bf16x8*)&z[cur][mt*16 + l15][kt*32 + quad*8];

    f32x4 acc[2][4];
    #pragma unroll
    for (int mt = 0; mt < 2; mt++)
      #pragma unroll
      for (int q = 0; q < 4; q++){
        f32x4 a = __builtin_amdgcn_mfma_f32_16x16x32_bf16(A[mt][0], B[q][0], zf, 0,0,0);
        a = __builtin_amdgcn_mfma_f32_16x16x32_bf16(A[mt][1], B[q][1], a, 0,0,0);
        a = __builtin_amdgcn_mfma_f32_16x16x32_bf16(A[mt][2], B[q][2], a, 0,0,0);
        a = __builtin_amdgcn_mfma_f32_16x16x32_bf16(A[mt][3], B[q][3], a, 0,0,0);
        a = __builtin_amdgcn_mfma_f32_16x16x32_bf16(A[mt][4], B[q][4], a, 0,0,0);
        acc[mt][q] = a;
      }

    #pragma unroll
    for (int mt = 0; mt < 2; mt++){
      f32x4 cv = cst[mt];
      #pragma unroll
      for (int r = 0; r < 4; r++){
        float gi = acc[mt][0][r] + bg[0];
        float gf = acc[mt][1][r] + bg[1];
        float gg = acc[mt][2][r] + bg[2];
        float go = acc[mt][3][r] + bg[3];
        float cc = sigf(gf)*cv[r] + sigf(gi)*tanhf_fast(gg);
        cv[r] = cc;
        float h = sigf(go)*tanhf_fast(cc);
        const int row = mt*16 + quad*4 + r;
        u16 hb = f2bf(h);
        z[nxt][row][DD + w*16 + l15] = hb;
        if (t == TT-1)
          node_h[(size_t)(nb + row)*HH + w*16 + l15] = hb;
      }
      cst[mt] = cv;
    }

    if (t + 1 < TT){
      z[nxt][n0][e0] = f2bf(xf0);
      if (has1) z[nxt][n1][e1] = f2bf(xf1);
    }
    __syncthreads();
  }
}

// ---------------- MFMA GEMM: Y[M,128] bf16 = X[M,128] bf16 @ Wf (B-frags) ---------------
__global__ __launch_bounds__(256) void gemm_kernel(const u16* __restrict__ X,
    const u16* __restrict__ Wf, u16* __restrict__ Y){
  __shared__ u16 xs[32][136];           // +8 pad
  const int tid = threadIdx.x, lane = tid & 63, w = tid >> 6;
  const int l15 = lane & 15, quad = lane >> 4;
  const int rb  = blockIdx.x*32;

  for (int c = tid; c < 512; c += 256){
    int row = c >> 4, cc = c & 15;
    *(bf16x8*)&xs[row][cc*8] = *(const bf16x8*)&X[(size_t)(rb+row)*128 + cc*8];
  }
  bf16x8 Bf[2][4];
  #pragma unroll
  for (int ct = 0; ct < 2; ct++)
    #pragma unroll
    for (int kt = 0; kt < 4; kt++)
      Bf[ct][kt] = *(const bf16x8*)&Wf[(size_t)((((2*w+ct)*4 + kt)*64 + lane))*8];
  __syncthreads();

  bf16x8 A[2][4];
  #pragma unroll
  for (int mt = 0; mt < 2; mt++)
    #pragma unroll
    for (int kt = 0; kt < 4; kt++)
      A[mt][kt] = *(const bf16x8*)&xs[mt*16 + l15][kt*32 + quad*8];

  const f32x4 zf = {0.f,0.f,0.f,0.f};
  #pragma unroll
  for (int mt = 0; mt < 2; mt++)
    #pragma unroll
    for (int ct = 0; ct < 2; ct++){
      f32x4 a = __builtin_amdgcn_mfma_f32_16x16x32_bf16(A[mt][0], Bf[ct][0], zf, 0,0,0);
      a = __builtin_amdgcn_mfma_f32_16x16x32_bf16(A[mt][1], Bf[ct][1], a, 0,0,0);
      a = __builtin_amdgcn_mfma_f32_16x16x32_bf16(A[mt][2], Bf[ct][2], a, 0,0,0);
      a = __builtin_amdgcn_mfma_f32_16x16x32_bf16(A[mt][3], Bf[ct][3], a, 0,0,0);
      #pragma unroll
      for (int r = 0; r < 4; r++)
        Y[(size_t)(rb + mt*16 + quad*4 + r)*128 + (2*w+ct)*16 + l15] = f2bf(a[r]);
    }
}

// ---------------- per-node attention logits asr/adt [N,4] (XH bf16, b128 loads) ---------
__global__ __launch_bounds__(256) void att_kernel(const u16* __restrict__ XH,
    const float* __restrict__ att_s, const float* __restrict__ att_d,
    float* __restrict__ asr, float* __restrict__ adt){
  __shared__ float as_[128], ad_[128];
  int tid = threadIdx.x;
  if (tid < 128){ as_[tid] = att_s[tid]; ad_[tid] = att_d[tid]; }
  __syncthreads();
  int n = blockIdx.x*64 + (tid>>2);
  int h = tid & 3;
  if (n >= NN) return;
  const u16* row = XH + (size_t)n*128 + h*32;
  float sv = 0.f, dv = 0.f;
  #pragma unroll
  for (int blk = 0; blk < 4; blk++){
    bf16x8 v = *(const bf16x8*)(row + blk*8);
    #pragma unroll
    for (int j = 0; j < 8; j++){
      float x = bf2f((u16)v[j]);
      sv = fmaf(x, as_[h*32 + blk*8 + j], sv);
      dv = fmaf(x, ad_[h*32 + blk*8 + j], dv);
    }
  }
  asr[n*4+h] = sv; adt[n*4+h] = dv;
}

// ---------------- CSR build (parallel scan) ---------------------------------------------
__device__ __forceinline__ void edge_sd(int e, const int* src, const int* dst, int& s, int& d){
  if (e < EE){ s = src[e]; d = dst[e]; } else { s = e - EE; d = s; }
}

__global__ void deg_kernel(const int* __restrict__ src, const int* __restrict__ dst,
                           int* __restrict__ deg){
  int e = blockIdx.x*256 + threadIdx.x;
  if (e >= EA) return;
  int s, d; edge_sd(e, src, dst, s, d);
  atomicAdd(deg + d, 1);
}

#define SCB 80   // ceil(NN/256)
__global__ __launch_bounds__(256) void psum_kernel(const int* __restrict__ deg,
                                                   int* __restrict__ psum){
  __shared__ int ws[4];
  int i = blockIdx.x*256 + threadIdx.x;
  int v = (i < NN) ? deg[i] : 0;
  #pragma unroll
  for (int off = 32; off > 0; off >>= 1) v += __shfl_down(v, off);
  if ((threadIdx.x & 63) == 0) ws[threadIdx.x >> 6] = v;
  __syncthreads();
  if (threadIdx.x == 0) psum[blockIdx.x] = ws[0]+ws[1]+ws[2]+ws[3];
}

__global__ void pscan_kernel(const int* __restrict__ psum, int* __restrict__ boff,
                             int* __restrict__ rowptr){
  if (threadIdx.x == 0){
    int acc = 0;
    for (int b = 0; b < SCB; b++){ boff[b] = acc; acc += psum[b]; }
    boff[SCB] = acc;
    rowptr[NN] = acc;   // == EA
  }
}

__global__ __launch_bounds__(256) void rowptr_kernel(const int* __restrict__ deg,
    const int* __restrict__ boff, int* __restrict__ rowptr, int* __restrict__ cursor){
  __shared__ int buf[256];
  const int tid = threadIdx.x;
  int i = blockIdx.x*256 + tid;
  int v = (i < NN) ? deg[i] : 0;
  buf[tid] = v;
  __syncthreads();
  #pragma unroll
  for (int off = 1; off < 256; off <<= 1){
    int t = (tid >= off) ? buf[tid - off] : 0;
    __syncthreads();
    buf[tid] += t;
    __syncthreads();
  }
  if (i < NN){
    int excl = buf[tid] - v + boff[blockIdx.x];
    rowptr[i] = excl; cursor[i] = excl;
  }
}

__global__ void fill_kernel(const int* __restrict__ src, const int* __restrict__ dst,
                            int* __restrict__ cursor, int* __restrict__ elist){
  int e = blockIdx.x*256 + threadIdx.x;
  if (e >= EA) return;
  int s, d; edge_sd(e, src, dst, s, d);
  int pos = atomicAdd(cursor + d, 1);
  elist[pos] = s;
}

// ---------------- fused GAT: 1-pass softmax+aggregate+bias+ELU (+optional head) ---------
__global__ __launch_bounds__(512) void gat_kernel(const int* __restrict__ rowptr,
    const int* __restrict__ elist, const float* __restrict__ asr,
    const float* __restrict__ adt, const u16* __restrict__ XH,
    const float* __restrict__ bias, u16* __restrict__ out,
    const float* __restrict__ Wh, const float* __restrict__ bh,
    float* __restrict__ outf){
  const int tid = threadIdx.x, lane = tid & 63, w = tid >> 6;
  const int d = blockIdx.x*8 + w;            // NN % 8 == 0
  const int r0 = rowptr[d], r1 = rowptr[d+1];
  const int h = lane >> 4;
  const int c = lane*2;
  float4 ad4 = *(const float4*)(adt + (size_t)d*4);
  const float adh = (h==0) ? ad4.x : (h==1) ? ad4.y : (h==2) ? ad4.z : ad4.w;

  float den = 0.f, accx = 0.f, accy = 0.f;
  // software-pipelined edge loop (>=1 edge guaranteed: self loop)
  int s_cur = elist[r0];
  float4 a_cur = *(const float4*)(asr + (size_t)s_cur*4);
  u32 pk_cur = ((const u32*)XH)[(size_t)s_cur*64 + lane];
  for (int idx = r0; idx < r1; idx++){
    int s_nxt = (idx+1 < r1) ? elist[idx+1] : s_cur;
    float4 a_nxt = *(const float4*)(asr + (size_t)s_nxt*4);
    u32 pk_nxt = ((const u32*)XH)[(size_t)s_nxt*64 + lane];
    float av = (h==0) ? a_cur.x : (h==1) ? a_cur.y : (h==2) ? a_cur.z : a_cur.w;
    float l = av + adh; l = l > 0.f ? l : 0.2f*l;
    float ex = __expf(l);
    den += ex;
    accx = fmaf(ex, bf2f((u16)pk_cur),       accx);
    accy = fmaf(ex, bf2f((u16)(pk_cur>>16)), accy);
    a_cur = a_nxt; pk_cur = pk_nxt; s_cur = s_nxt;
  }
  float rd = __builtin_amdgcn_rcpf(den);
  float vx = accx*rd + bias[c], vy = accy*rd + bias[c+1];
  vx = vx > 0.f ? vx : __expf(vx) - 1.f;
  vy = vy > 0.f ? vy : __expf(vy) - 1.f;

  if (Wh == nullptr){
    u32 pk = (u32)f2bf(vx) | ((u32)f2bf(vy) << 16);
    ((u32*)out)[(size_t)d*64 + lane] = pk;
  } else {
    float p0 = vx*Wh[c*2]   + vy*Wh[c*2+2];
    float p1 = vx*Wh[c*2+1] + vy*Wh[c*2+3];
    #pragma unroll
    for (int off = 32; off > 0; off >>= 1){
      p0 += __shfl_xor(p0, off);
      p1 += __shfl_xor(p1, off);
    }
    if (lane == 0){
      float2 o; o.x = p0 + bh[0]; o.y = p1 + bh[1];
      ((float2*)outf)[d] = o;
    }
  }
}

// ---------------- launch ----------------------------------------------------------------
extern "C" void kernel_launch(void* const* d_in, const int* in_sizes, int n_in,
                              void* d_out, int out_size, void* d_ws, size_t ws_size,
                              hipStream_t stream){
  const float* xwin = (const float*)d_in[0];
  const int*   eidx = (const int*)d_in[1];
  const float* Wih  = (const float*)d_in[2];
  const float* Whh  = (const float*)d_in[3];
  const float* bih  = (const float*)d_in[4];
  const float* bhh  = (const float*)d_in[5];
  const float* W1   = (const float*)d_in[6];
  const float* as1  = (const float*)d_in[7];
  const float* ad1  = (const float*)d_in[8];
  const float* b1   = (const float*)d_in[9];
  const float* W2   = (const float*)d_in[10];
  const float* as2  = (const float*)d_in[11];
  const float* ad2  = (const float*)d_in[12];
  const float* b2   = (const float*)d_in[13];
  const float* Wh   = (const float*)d_in[14];
  const float* bh   = (const float*)d_in[15];
  const int* src = eidx;
  const int* dst = eidx + EE;

  char* ws = (char*)d_ws;
  size_t off = 0;
  auto alloc = [&](size_t bytes)->void*{
    void* p = ws + off; off += (bytes + 255) & ~(size_t)255; return p;
  };
  u16*   WfL   = (u16*)  alloc((size_t)8*4*5*64*8*sizeof(u16));
  u16*   W1f   = (u16*)  alloc((size_t)8*4*64*8*sizeof(u16));
  u16*   W2f   = (u16*)  alloc((size_t)8*4*64*8*sizeof(u16));
  float* bias  = (float*)alloc(512*sizeof(float));
  u16*   nodeh = (u16*)  alloc((size_t)NN*128*sizeof(u16));
  u16*   xh    = (u16*)  alloc((size_t)NN*128*sizeof(u16));
  u16*   hbuf  = (u16*)  alloc((size_t)NN*128*sizeof(u16));
  float* asr   = (float*)alloc((size_t)NN*4*sizeof(float));
  float* adt   = (float*)alloc((size_t)NN*4*sizeof(float));
  int*   deg   = (int*)  alloc((size_t)NN*sizeof(int));
  int*   rowp  = (int*)  alloc((size_t)(NN+1)*sizeof(int));
  int*   curs  = (int*)  alloc((size_t)NN*sizeof(int));
  int*   psum  = (int*)  alloc((size_t)SCB*sizeof(int));
  int*   boff  = (int*)  alloc((size_t)(SCB+1)*sizeof(int));
  int*   elist = (int*)  alloc((size_t)EA*sizeof(int));
  (void)ws_size; (void)in_sizes; (void)n_in; (void)out_size;

  const int EGRID = (EA+255)/256;

  // weight prep + CSR build
  prep_lstm_kernel<<<(8*4*5*64*8+255)/256, 256, 0, stream>>>(Wih, Whh, bih, bhh, WfL, bias);
  prep_w_kernel<<<(2*8*4*64*8+255)/256, 256, 0, stream>>>(W1, W2, W1f, W2f);
  hipMemsetAsync(deg, 0, (size_t)NN*sizeof(int), stream);
  deg_kernel<<<EGRID, 256, 0, stream>>>(src, dst, deg);
  psum_kernel<<<SCB, 256, 0, stream>>>(deg, psum);
  pscan_kernel<<<1, 64, 0, stream>>>(psum, boff, rowp);
  rowptr_kernel<<<SCB, 256, 0, stream>>>(deg, boff, rowp, curs);
  fill_kernel<<<EGRID, 256, 0, stream>>>(src, dst, curs, elist);

  // LSTM
  lstm_kernel<<<NN/32, 512, 0, stream>>>(xwin, WfL, bias, nodeh);

  // GAT layer 1
  gemm_kernel<<<NN/32, 256, 0, stream>>>(nodeh, W1f, xh);
  att_kernel<<<(NN+63)/64, 256, 0, stream>>>(xh, as1, ad1, asr, adt);
  gat_kernel<<<NN/8, 512, 0, stream>>>(rowp, elist, asr, adt, xh, b1, hbuf,
                                       nullptr, nullptr, nullptr);
  // GAT layer 2 (+fused head)
  gemm_kernel<<<NN/32, 256, 0, stream>>>(hbuf, W2f, xh);
  att_kernel<<<(NN+63)/64, 256, 0, stream>>>(xh, as2, ad2, asr, adt);
  gat_kernel<<<NN/8, 512, 0, stream>>>(rowp, elist, asr, adt, xh, b2, nullptr,
                                       Wh, bh, (float*)d_out);
}